// Round 10
// baseline (142061.218 us; speedup 1.0000x reference)
//
#include <hip/hip_runtime.h>
#include <hip/hip_cooperative_groups.h>
#include <hip/hip_bf16.h>
#include <math.h>

namespace cg = cooperative_groups;

#define T_   2048
#define N_   128
#define NS_  64
#define NA_  8
#define NFC_ 128
#define NH_  128
#define DX_  192
#define DP_  16
#define DM_  256
#define G3_  384
#define G4_  512

// ---------------- bf16 helpers ----------------
template<int NW>
__device__ __forceinline__ float dot_bf16T(const __hip_bfloat16* __restrict__ w,
                                           const float* __restrict__ x) {
  const uint4* wv = reinterpret_cast<const uint4*>(w);
  const float4* xv = reinterpret_cast<const float4*>(x);
  float a0 = 0.f, a1 = 0.f, a2 = 0.f, a3 = 0.f;
  #pragma unroll
  for (int i = 0; i < NW; ++i) {
    uint4 u = wv[i];
    float4 x0 = xv[2 * i];
    float4 x1 = xv[2 * i + 1];
    a0 = fmaf(__uint_as_float(u.x << 16),          x0.x, a0);
    a1 = fmaf(__uint_as_float(u.x & 0xffff0000u),  x0.y, a1);
    a2 = fmaf(__uint_as_float(u.y << 16),          x0.z, a2);
    a3 = fmaf(__uint_as_float(u.y & 0xffff0000u),  x0.w, a3);
    a0 = fmaf(__uint_as_float(u.z << 16),          x1.x, a0);
    a1 = fmaf(__uint_as_float(u.z & 0xffff0000u),  x1.y, a1);
    a2 = fmaf(__uint_as_float(u.w << 16),          x1.z, a2);
    a3 = fmaf(__uint_as_float(u.w & 0xffff0000u),  x1.w, a3);
  }
  return (a0 + a1) + (a2 + a3);
}

// 8-elem bf16 dot: one uint4 of weights vs 8 floats (aligned 32B)
__device__ __forceinline__ float dot8(uint4 u, const float4* __restrict__ x2) {
  float4 x0 = x2[0], x1 = x2[1];
  float a0 = 0.f, a1 = 0.f;
  a0 = fmaf(__uint_as_float(u.x << 16),          x0.x, a0);
  a1 = fmaf(__uint_as_float(u.x & 0xffff0000u),  x0.y, a1);
  a0 = fmaf(__uint_as_float(u.y << 16),          x0.z, a0);
  a1 = fmaf(__uint_as_float(u.y & 0xffff0000u),  x0.w, a1);
  a0 = fmaf(__uint_as_float(u.z << 16),          x1.x, a0);
  a1 = fmaf(__uint_as_float(u.z & 0xffff0000u),  x1.y, a1);
  a0 = fmaf(__uint_as_float(u.w << 16),          x1.z, a0);
  a1 = fmaf(__uint_as_float(u.w & 0xffff0000u),  x1.w, a1);
  return a0 + a1;
}

__device__ __forceinline__ float sigm(float x) { return 1.f / (1.f + expf(-x)); }

__device__ __forceinline__ void spin_ge(int* f, int want) {
  if (__hip_atomic_load(f, __ATOMIC_ACQUIRE, __HIP_MEMORY_SCOPE_AGENT) >= want) return;
  int g = 0;
  while (__hip_atomic_load(f, __ATOMIC_RELAXED, __HIP_MEMORY_SCOPE_AGENT) < want) {
    __builtin_amdgcn_s_sleep(2);
    if (++g > (1 << 27)) break;
  }
  int v = __hip_atomic_load(f, __ATOMIC_ACQUIRE, __HIP_MEMORY_SCOPE_AGENT);
  asm volatile("" :: "v"(v));
}

// LDS-only barrier: does NOT drain vmcnt -> prefetched global loads stay in flight.
// Safe here: all in-loop barriers guard LDS state only; global visibility is
// carried by __threadfence before release-stores + spin_ge's acquire (L1 inv).
__device__ __forceinline__ void bar_l() {
  asm volatile("s_waitcnt lgkmcnt(0)" ::: "memory");
  __builtin_amdgcn_s_barrier();
  asm volatile("" ::: "memory");
}

struct Params {
  const float* obs; const float* fps; const float* dones; const float* states0;
  const float* b_fcx; const float* b_fcp; const float* b_fcm;
  const float* a_src; const float* a_dst;
  const float* b_lstm; const float* b_act;
  const float* W_cri; const float* b_cri;
  const int* acts; const int* nbr;
  float* out;
  float* h_buf;    // [2][N][NH]
  float* Wh_buf;   // [2][N][G3]
  float* psrc;     // [2][N][2]
  float* pdst;     // [2][N][2]
  int* flag_h;     // [256*16]
  int* flag_w;     // [256*16]
  const __hip_bfloat16* lstmT; // [N][G4][512] = [ih(384)|hh(128)]
  const __hip_bfloat16* gatT;  // [G3][G3]
  const __hip_bfloat16* fcxT;  // [N][NFC][DX]
  const __hip_bfloat16* fcpT;  // [N][NFC][DP]
  const __hip_bfloat16* fcmT;  // [N][NFC][DM]
  const __hip_bfloat16* actT;  // [N][NA][NH]
  const __hip_bfloat16* xp;    // [T][N][256] precomputed x|p feats (bf16)
  int use_xp;
};

// ---------------- prep kernels ----------------
__global__ void transpose_to_bf16(const float* __restrict__ src, __hip_bfloat16* __restrict__ dst,
                                  int A, int D, int G) {
  size_t total = (size_t)A * D * G;
  size_t stride = (size_t)gridDim.x * blockDim.x;
  for (size_t i = (size_t)blockIdx.x * blockDim.x + threadIdx.x; i < total; i += stride) {
    size_t dg = (size_t)D * G;
    size_t a = i / dg;
    size_t r = i - a * dg;
    size_t g = r / D, d = r - g * D;
    dst[i] = __float2bfloat16(src[a * dg + d * G + g]);
  }
}

__global__ void build_lstmT(const float* __restrict__ Wih, const float* __restrict__ Whh,
                            __hip_bfloat16* __restrict__ dst) {
  size_t total = (size_t)N_ * G4_ * 512;
  size_t stride = (size_t)gridDim.x * blockDim.x;
  for (size_t i = (size_t)blockIdx.x * blockDim.x + threadIdx.x; i < total; i += stride) {
    int d = (int)(i & 511);
    size_t r = i >> 9;
    int g = (int)(r & 511);
    int n = (int)(r >> 9);
    float v = (d < G3_) ? Wih[((size_t)n * G3_ + d) * G4_ + g]
                        : Whh[((size_t)n * NH_ + (d - G3_)) * G4_ + g];
    dst[i] = __float2bfloat16(v);
  }
}

__global__ void reset_flags(int* flag_h, int* flag_w) {
  int i = blockIdx.x * blockDim.x + threadIdx.x;
  if (i < 256 * 16) { flag_h[i] = 0; flag_w[i] = 0; }
}

// precompute x,p feats for all t (h-independent): xp[t][n][0..127]=x, [128..255]=p
__global__ void build_xp(const float* __restrict__ obs, const float* __restrict__ fps,
                         const __hip_bfloat16* __restrict__ fcxT,
                         const __hip_bfloat16* __restrict__ fcpT,
                         const float* __restrict__ b_fcx, const float* __restrict__ b_fcp,
                         const int* __restrict__ nbr, __hip_bfloat16* __restrict__ xp) {
  const int n = blockIdx.x, tc = blockIdx.y, tid = threadIdx.x;
  const int nb0 = nbr[n * 2], nb1 = nbr[n * 2 + 1];
  __shared__ __align__(16) float xin[DX_];
  __shared__ __align__(16) float pin[DP_];
  for (int tt = 0; tt < T_ / 16; ++tt) {
    int t = tc * (T_ / 16) + tt;
    if (tid < DX_) {
      int k = tid >> 6, d = tid & 63;
      int ag = (k == 0) ? n : ((k == 1) ? nb0 : nb1);
      xin[tid] = obs[((size_t)t * N_ + ag) * NS_ + d];
    } else if (tid < DX_ + DP_) {
      int u = tid - DX_;
      int k = u >> 3, a = u & 7;
      pin[u] = fps[((size_t)t * N_ + (k ? nb1 : nb0)) * NA_ + a];
    }
    __syncthreads();
    if (tid < 128) {
      float acc = b_fcx[n * NFC_ + tid]
                + dot_bf16T<24>(fcxT + ((size_t)n * NFC_ + tid) * DX_, xin);
      xp[((size_t)t * N_ + n) * 256 + tid] = __float2bfloat16(fmaxf(acc, 0.f));
    } else if (tid < 256) {
      int r = tid - 128;
      float acc = b_fcp[n * NFC_ + r]
                + dot_bf16T<2>(fcpT + ((size_t)n * NFC_ + r) * DP_, pin);
      xp[((size_t)t * N_ + n) * 256 + 128 + r] = __float2bfloat16(fmaxf(acc, 0.f));
    }
    __syncthreads();
  }
}

// heads for timestep th. H==0: actor, H==1: critic.
__device__ __forceinline__ void do_heads(const Params& p, int n, int H, int tid, int th,
                                         const float* sh_h, int nb0, int nb1) {
  if (tid >= 64) return;
  if (H == 0) {
    int a = tid >> 3, k = tid & 7;
    const uint4* wv = reinterpret_cast<const uint4*>(p.actT + ((size_t)n * NA_ + a) * NH_);
    const float4* xv = reinterpret_cast<const float4*>(sh_h);
    float pp = 0.f;
    #pragma unroll
    for (int i = 0; i < 2; ++i) {
      pp += dot8(wv[k * 2 + i], xv + (k * 2 + i) * 2);
    }
    pp += __shfl_down(pp, 4, 8);
    pp += __shfl_down(pp, 2, 8);
    pp += __shfl_down(pp, 1, 8);
    if (k == 0) p.out[((size_t)th * N_ + n) * 9 + a] = pp + p.b_act[n * NA_ + a];
  } else {
    const float* wc = p.W_cri + (size_t)n * 144;
    float pp = sh_h[tid] * wc[tid] + sh_h[64 + tid] * wc[64 + tid];
    for (int off = 32; off; off >>= 1) pp += __shfl_down(pp, off);
    if (tid == 0) {
      pp += p.b_cri[n];
      pp += wc[NH_ + p.acts[(size_t)th * N_ + nb0]];
      pp += wc[NH_ + NA_ + p.acts[(size_t)th * N_ + nb1]];
      p.out[((size_t)th * N_ + n) * 9 + 8] = pp;
    }
  }
}

// ---- main: 256 WGs (2/agent) x 1024 thr; cross-phase prefetch of t-invariant weights ----
__global__ void __launch_bounds__(1024, 4) policy_scan_v10(Params p) {
  const int tid  = threadIdx.x;
  const int wid  = tid >> 6;
  const int lane = tid & 63;
  const int bid = blockIdx.x;
  const int bl  = bid & 127;
  const int n   = ((bl & 7) << 4) | (bl >> 3);   // cluster ring on XCD
  const int H   = bid >> 7;                      // agent half; partner same XCD
  const int nb0 = p.nbr[n * 2 + 0];
  const int nb1 = p.nbr[n * 2 + 1];
  const int bl0 = ((nb0 & 15) << 3) | (nb0 >> 4);
  const int bl1 = ((nb1 & 15) << 3) | (nb1 >> 4);
  const int wg_partner = bid ^ 128;
  const int w0 = wg_partner, w1 = bl0, w2 = bl0 + 128, w3 = bl1, w4 = bl1 + 128;

  // LDS: 128KB lstm cache ([row][chunk], 128 rows x 64 uint4) + buffers
  __shared__ __align__(16) uint4 wlds[128 * 64];
  __shared__ __align__(16) float sh_h[NH_];
  __shared__ __align__(16) float sh_c[64];
  __shared__ __align__(16) float sh_xin[DX_];
  __shared__ __align__(16) float sh_pin[DP_];
  __shared__ __align__(16) float sh_min[DM_];
  __shared__ __align__(16) float sh_feat[G3_];
  __shared__ __align__(16) float sh_sx[512];     // [sgat(384) | masked own h(128)]
  __shared__ __align__(16) float sh_gates[256];
  __shared__ __align__(16) float red_s[192];
  __shared__ __align__(16) float red_d[192];

  // preload lstm cache rows 0..127 (gates i,f) into wlds[row][chunk]
  {
    int row = tid >> 3;             // 0..127
    int c0  = (tid & 7) * 8;        // 8 consecutive chunks per thread
    int growr = ((row >> 6) << 7) + H * 64 + (row & 63);
    const uint4* src = reinterpret_cast<const uint4*>(
        p.lstmT + ((size_t)n * G4_ + growr) * 512);
    #pragma unroll
    for (int j = 0; j < 8; ++j) wlds[row * 64 + c0 + j] = src[c0 + j];
  }

  // prologue
  if (tid < 64) {
    sh_c[tid] = p.states0[n * (2 * NH_) + NH_ + H * 64 + tid];
    p.h_buf[n * NH_ + H * 64 + tid] = p.states0[n * (2 * NH_) + H * 64 + tid];
  }
  __syncthreads();
  if (tid == 0) {
    __threadfence();
    __hip_atomic_store(&p.flag_h[bid * 16], 1, __ATOMIC_RELEASE, __HIP_MEMORY_SCOPE_AGENT);
  }

  for (int t = 0; t < T_; ++t) {
    const float keep  = 1.f - p.dones[(size_t)t * N_ + n];
    const float keep0 = 1.f - p.dones[(size_t)t * N_ + nb0];
    const float keep1 = 1.f - p.dones[(size_t)t * N_ + nb1];

    const float* hb_r = p.h_buf  + (size_t)(t & 1) * N_ * NH_;
    float*       hb_w = p.h_buf  + (size_t)((t + 1) & 1) * N_ * NH_;
    float*       whb  = p.Wh_buf + (size_t)(t & 1) * N_ * G3_;
    float*       psb  = p.psrc   + (size_t)(t & 1) * N_ * 2;
    float*       pdb  = p.pdst   + (size_t)(t & 1) * N_ * 2;

    // ---- P: prefetch t-invariant streamed weights (consumed in C and F).
    // Loads stay in flight across LGKM-only barriers; values arrive by use time.
    uint4 pf0, pf1, pf2, pf3, pf4, pf5, pf6, pf7;   // F: streamed LSTM rows
    uint4 pm0, pm1, pm2, pm3;                       // C: fcm rows
    {
      #define LD_F(i, dst) { int ridx = 128 + wid * 8 + i; \
        int gr = ((ridx >> 6) << 7) + H * 64 + (ridx & 63); \
        dst = reinterpret_cast<const uint4*>(p.lstmT + ((size_t)n * G4_ + gr) * 512)[lane]; }
      LD_F(0, pf0) LD_F(1, pf1) LD_F(2, pf2) LD_F(3, pf3)
      LD_F(4, pf4) LD_F(5, pf5) LD_F(6, pf6) LD_F(7, pf7)
      #undef LD_F
      int cl = lane & 31;
      #define LD_M(pp, dst) { int r = wid * 8 + pp * 2 + (lane >> 5); \
        dst = reinterpret_cast<const uint4*>(p.fcmT + ((size_t)n * NFC_ + r) * DM_)[cl]; }
      LD_M(0, pm0) LD_M(1, pm1) LD_M(2, pm2) LD_M(3, pm3)
      #undef LD_M
    }

    // ---- A: feat/x-p staging + flag_h waits ----
    if (p.use_xp) {
      if (tid < 256) sh_feat[tid] = __bfloat162float(p.xp[((size_t)t * N_ + n) * 256 + tid]);
    } else {
      if (tid < DX_) {
        int k = tid >> 6, d = tid & 63;
        int agent = (k == 0) ? n : ((k == 1) ? nb0 : nb1);
        sh_xin[tid] = p.obs[((size_t)t * N_ + agent) * NS_ + d];
      } else if (tid < DX_ + DP_) {
        int u = tid - DX_;
        int k = u >> 3, a = u & 7;
        sh_pin[u] = p.fps[((size_t)t * N_ + (k ? nb1 : nb0)) * NA_ + a];
      }
    }
    if (tid >= 960 && tid < 965) {
      int u = tid - 960;
      int wid5 = (u == 0) ? w0 : (u == 1) ? w1 : (u == 2) ? w2 : (u == 3) ? w3 : w4;
      spin_ge(p.flag_h + wid5 * 16, t + 1);
    }
    bar_l();   // b1

    // ---- B: h staging ----
    if (tid < NH_) {
      sh_h[tid] = hb_r[n * NH_ + tid];
    } else if (tid < 384) {
      int v = tid - 128;
      int k = v >> 7, f = v & 127;
      int agent = (k == 0) ? nb0 : nb1;
      float kp  = (k == 0) ? keep0 : keep1;
      sh_min[v] = hb_r[agent * NH_ + f] * kp;
    } else if (tid < 512) {
      int f = tid - 384;
      sh_sx[G3_ + f] = hb_r[n * NH_ + f] * keep;
    }
    bar_l();   // b2

    // ---- C: heads(t-1) on wave0, then fcm from prefetched regs ----
    if (wid == 0 && t > 0) do_heads(p, n, H, lane, t - 1, sh_h, nb0, nb1);

    {
      const float4* xm = reinterpret_cast<const float4*>(sh_min);
      int cl = lane & 31;
      #define FCM_PASS(pp, u) { int r = wid * 8 + pp * 2 + (lane >> 5); \
        float s = dot8(u, xm + cl * 2); \
        s += __shfl_down(s, 16); s += __shfl_down(s, 8); s += __shfl_down(s, 4); \
        s += __shfl_down(s, 2);  s += __shfl_down(s, 1); \
        if ((lane & 31) == 0) sh_feat[256 + r] = fmaxf(s + p.b_fcm[n * NFC_ + r], 0.f); }
      FCM_PASS(0, pm0) FCM_PASS(1, pm1) FCM_PASS(2, pm2) FCM_PASS(3, pm3)
      #undef FCM_PASS
    }
    if (!p.use_xp) {
      const float4* xx = reinterpret_cast<const float4*>(sh_xin);
      #pragma unroll
      for (int pp = 0; pp < 8; ++pp) {
        int r = wid * 8 + pp;
        float s = 0.f;
        if (lane < 24) {
          uint4 u = reinterpret_cast<const uint4*>(p.fcxT + ((size_t)n * NFC_ + r) * DX_)[lane];
          s = dot8(u, xx + lane * 2);
        }
        for (int off = 32; off; off >>= 1) s += __shfl_down(s, off);
        if (lane == 0) sh_feat[r] = fmaxf(s + p.b_fcx[n * NFC_ + r], 0.f);
      }
      if (tid < 128) {
        float acc = p.b_fcp[n * NFC_ + tid]
                  + dot_bf16T<2>(p.fcpT + ((size_t)n * NFC_ + tid) * DP_, sh_pin);
        sh_feat[128 + tid] = fmaxf(acc, 0.f);
      }
    }
    bar_l();   // b3

    // ---- D: gat own 192 rows, wave-cooperative (12 rows/wave, L2-shared table) ----
    {
      const float4* xf = reinterpret_cast<const float4*>(sh_feat);
      #pragma unroll
      for (int pp = 0; pp < 12; ++pp) {
        int r = wid * 12 + pp;
        int row = H * 192 + r;
        float s = 0.f;
        if (lane < 48) {
          uint4 u = reinterpret_cast<const uint4*>(p.gatT + (size_t)row * G3_)[lane];
          s = dot8(u, xf + lane * 2);
        }
        for (int off = 32; off; off >>= 1) s += __shfl_down(s, off);
        if (lane == 0) {
          whb[n * G3_ + row] = s;
          red_s[r] = s * p.a_src[row];
          red_d[r] = s * p.a_dst[row];
        }
      }
    }
    bar_l();   // b4

    // ---- D4: wave0 src/dst reduce + publish flag_w; spinners wait ----
    if (wid == 0) {
      float s = red_s[lane] + red_s[lane + 64] + red_s[lane + 128];
      for (int off = 32; off; off >>= 1) s += __shfl_down(s, off);
      float d = red_d[lane] + red_d[lane + 64] + red_d[lane + 128];
      for (int off = 32; off; off >>= 1) d += __shfl_down(d, off);
      if (lane == 0) {
        psb[n * 2 + H] = s;
        pdb[n * 2 + H] = d;
        __threadfence();
        __hip_atomic_store(&p.flag_w[bid * 16], t + 1, __ATOMIC_RELEASE, __HIP_MEMORY_SCOPE_AGENT);
      }
    } else if (tid >= 960 && tid < 965) {
      int u = tid - 960;
      int wid5 = (u == 0) ? w0 : (u == 1) ? w1 : (u == 2) ? w2 : (u == 3) ? w3 : w4;
      spin_ge(p.flag_w + wid5 * 16, t + 1);
    }
    bar_l();   // b5

    // ---- E: attention + sgat ----
    {
      float src_n = psb[n * 2] + psb[n * 2 + 1];
      float e_l = src_n + pdb[nb0 * 2] + pdb[nb0 * 2 + 1];
      float e_s = src_n + pdb[n   * 2] + pdb[n   * 2 + 1];
      float e_r = src_n + pdb[nb1 * 2] + pdb[nb1 * 2 + 1];
      e_l = (e_l >= 0.f) ? e_l : 0.2f * e_l;
      e_s = (e_s >= 0.f) ? e_s : 0.2f * e_s;
      e_r = (e_r >= 0.f) ? e_r : 0.2f * e_r;
      float mx = fmaxf(e_l, fmaxf(e_s, e_r));
      float wl = expf(e_l - mx), wsf = expf(e_s - mx), wr = expf(e_r - mx);
      float inv = 1.f / (wl + wsf + wr);
      wl *= inv; wsf *= inv; wr *= inv;
      if (tid < G3_) {
        float v = wsf * whb[n   * G3_ + tid]
                + wl  * whb[nb0 * G3_ + tid]
                + wr  * whb[nb1 * G3_ + tid];
        sh_sx[tid] = (v > 0.f) ? v : expm1f(v);
      }
    }
    bar_l();   // b6

    // ---- F: LSTM gates. 16 rows/wave: 8 LDS-cached + 8 prefetched regs ----
    {
      const float4* xv = reinterpret_cast<const float4*>(sh_sx);
      #pragma unroll
      for (int pp = 0; pp < 8; ++pp) {
        int ridx = wid * 8 + pp;
        uint4 u = wlds[ridx * 64 + lane];
        float s = dot8(u, xv + lane * 2);
        for (int off = 32; off; off >>= 1) s += __shfl_down(s, off);
        if (lane == 0) {
          int gr = ((ridx >> 6) << 7) + H * 64 + (ridx & 63);
          sh_gates[ridx] = s + p.b_lstm[n * G4_ + gr];
        }
      }
      #define DO_SROW(i, src) { int ridx = 128 + wid * 8 + i; \
        float s = dot8(src, xv + lane * 2); \
        for (int off = 32; off; off >>= 1) s += __shfl_down(s, off); \
        if (lane == 0) { int gr = ((ridx >> 6) << 7) + H * 64 + (ridx & 63); \
          sh_gates[ridx] = s + p.b_lstm[n * G4_ + gr]; } }
      DO_SROW(0, pf0) DO_SROW(1, pf1) DO_SROW(2, pf2) DO_SROW(3, pf3)
      DO_SROW(4, pf4) DO_SROW(5, pf5) DO_SROW(6, pf6) DO_SROW(7, pf7)
      #undef DO_SROW
    }
    bar_l();   // b7

    // ---- G: wave0 state update + publish h half ----
    if (wid == 0) {
      float gi = sh_gates[lane];
      float gf = sh_gates[64 + lane];
      float gg = sh_gates[128 + lane];
      float go = sh_gates[192 + lane];
      float c_new = sigm(gf) * (sh_c[lane] * keep) + sigm(gi) * tanhf(gg);
      float h_new = sigm(go) * tanhf(c_new);
      sh_c[lane] = c_new;
      hb_w[n * NH_ + H * 64 + lane] = h_new;
      if (lane == 0) {
        __threadfence();   // drains wave0's vmcnt: hb_w store visible before flag
        __hip_atomic_store(&p.flag_h[bid * 16], t + 2, __ATOMIC_RELEASE, __HIP_MEMORY_SCOPE_AGENT);
      }
    }
    // no trailing barrier: b1 of next iteration synchronizes; A touches disjoint LDS
  }

  // ---- tail: heads for t = T-1 ----
  if (tid == 0) spin_ge(p.flag_h + wg_partner * 16, T_ + 1);
  __syncthreads();
  if (tid < NH_) sh_h[tid] = p.h_buf[(size_t)(T_ & 1) * N_ * NH_ + n * NH_ + tid];
  __syncthreads();
  do_heads(p, n, H, tid, T_ - 1, sh_h, nb0, nb1);
}

// ---------------- fallback: fp32 grid-sync kernel (ws too small) ----------------
struct ParamsF {
  const float* obs; const float* fps; const float* dones; const float* states0;
  const float* W_fcx; const float* b_fcx;
  const float* W_fcp; const float* b_fcp;
  const float* W_fcm; const float* b_fcm;
  const float* W_gat; const float* a_src; const float* a_dst;
  const float* W_ih;  const float* W_hh;  const float* b_lstm;
  const float* W_act; const float* b_act;
  const float* W_cri; const float* b_cri;
  const int* acts; const int* nbr;
  float* out; float* h_buf; float* Wh_buf; float* dst_buf;
};

__global__ void __launch_bounds__(512) policy_scan_f32(ParamsF p) {
  cg::grid_group grid = cg::this_grid();
  const int tid = threadIdx.x;
  const int n   = blockIdx.x;
  const int nb0 = p.nbr[n * 2 + 0];
  const int nb1 = p.nbr[n * 2 + 1];
  __shared__ float sh_h[NH_], sh_c[NH_], sh_xin[DX_], sh_pin[DP_], sh_min[DM_];
  __shared__ float sh_feat[G3_], sh_Wh[G3_], sh_sgat[G3_], sh_gates[G4_], sh_src;
  if (tid < NH_) {
    float h0 = p.states0[n * (2 * NH_) + tid];
    float c0 = p.states0[n * (2 * NH_) + NH_ + tid];
    sh_h[tid] = h0; sh_c[tid] = c0; p.h_buf[n * NH_ + tid] = h0;
  }
  __threadfence();
  grid.sync();
  for (int t = 0; t < T_; ++t) {
    const float keep  = 1.f - p.dones[(size_t)t * N_ + n];
    const float keep0 = 1.f - p.dones[(size_t)t * N_ + nb0];
    const float keep1 = 1.f - p.dones[(size_t)t * N_ + nb1];
    if (tid < NH_) { sh_h[tid] *= keep; sh_c[tid] *= keep; }
    if (tid < DX_) {
      int k = tid >> 6, d = tid & 63;
      int agent = (k == 0) ? n : ((k == 1) ? nb0 : nb1);
      sh_xin[tid] = p.obs[((size_t)t * N_ + agent) * NS_ + d];
    }
    {
      int u = tid - DX_;
      if (u >= 0 && u < DP_) {
        int k = u >> 3, a = u & 7;
        sh_pin[u] = p.fps[((size_t)t * N_ + ((k == 0) ? nb0 : nb1)) * NA_ + a];
      }
      int v = tid - (DX_ + DP_);
      if (v >= 0 && v < DM_) {
        int k = v >> 7, f = v & 127;
        sh_min[v] = p.h_buf[((k == 0) ? nb0 : nb1) * NH_ + f] * ((k == 0) ? keep0 : keep1);
      }
    }
    __syncthreads();
    if (tid < NFC_) {
      const float* w = p.W_fcx + ((size_t)n * DX_) * NFC_ + tid;
      float acc = p.b_fcx[n * NFC_ + tid];
      #pragma unroll 4
      for (int d = 0; d < DX_; ++d) acc = fmaf(sh_xin[d], w[(size_t)d * NFC_], acc);
      sh_feat[tid] = fmaxf(acc, 0.f);
    } else if (tid < 2 * NFC_) {
      int f = tid - NFC_;
      const float* w = p.W_fcp + ((size_t)n * DP_) * NFC_ + f;
      float acc = p.b_fcp[n * NFC_ + f];
      #pragma unroll
      for (int d = 0; d < DP_; ++d) acc = fmaf(sh_pin[d], w[(size_t)d * NFC_], acc);
      sh_feat[NFC_ + f] = fmaxf(acc, 0.f);
    } else if (tid < 3 * NFC_) {
      int f = tid - 2 * NFC_;
      const float* w = p.W_fcm + ((size_t)n * DM_) * NFC_ + f;
      float acc = p.b_fcm[n * NFC_ + f];
      #pragma unroll 4
      for (int d = 0; d < DM_; ++d) acc = fmaf(sh_min[d], w[(size_t)d * NFC_], acc);
      sh_feat[2 * NFC_ + f] = fmaxf(acc, 0.f);
    }
    __syncthreads();
    if (tid < G3_) {
      const float* w = p.W_gat + tid;
      float acc = 0.f;
      #pragma unroll 4
      for (int d = 0; d < G3_; ++d) acc = fmaf(sh_feat[d], w[(size_t)d * G3_], acc);
      sh_Wh[tid] = acc;
      p.Wh_buf[n * G3_ + tid] = acc;
    }
    __syncthreads();
    if (tid < 64) {
      float s = 0.f;
      for (int g = tid; g < G3_; g += 64) s += sh_Wh[g] * p.a_src[g];
      for (int off = 32; off; off >>= 1) s += __shfl_down(s, off);
      if (tid == 0) sh_src = s;
    } else if (tid < 128) {
      int l = tid - 64;
      float s = 0.f;
      for (int g = l; g < G3_; g += 64) s += sh_Wh[g] * p.a_dst[g];
      for (int off = 32; off; off >>= 1) s += __shfl_down(s, off);
      if (l == 0) p.dst_buf[n] = s;
    }
    __threadfence();
    grid.sync();
    const float src_n = sh_src;
    float e_l = src_n + p.dst_buf[nb0];
    float e_s = src_n + p.dst_buf[n];
    float e_r = src_n + p.dst_buf[nb1];
    e_l = (e_l >= 0.f) ? e_l : 0.2f * e_l;
    e_s = (e_s >= 0.f) ? e_s : 0.2f * e_s;
    e_r = (e_r >= 0.f) ? e_r : 0.2f * e_r;
    float mx = fmaxf(e_l, fmaxf(e_s, e_r));
    float wl = expf(e_l - mx), wsf = expf(e_s - mx), wr = expf(e_r - mx);
    float inv = 1.f / (wl + wsf + wr);
    wl *= inv; wsf *= inv; wr *= inv;
    if (tid < G3_) {
      float v = wsf * sh_Wh[tid] + wl * p.Wh_buf[nb0 * G3_ + tid] + wr * p.Wh_buf[nb1 * G3_ + tid];
      sh_sgat[tid] = (v > 0.f) ? v : expm1f(v);
    }
    __syncthreads();
    {
      const int g = tid;
      const float* wih = p.W_ih + ((size_t)n * G3_) * G4_ + g;
      const float* whh = p.W_hh + ((size_t)n * NH_) * G4_ + g;
      float acc = p.b_lstm[n * G4_ + g];
      #pragma unroll 4
      for (int d = 0; d < G3_; ++d) acc = fmaf(sh_sgat[d], wih[(size_t)d * G4_], acc);
      #pragma unroll 4
      for (int d = 0; d < NH_; ++d) acc = fmaf(sh_h[d], whh[(size_t)d * G4_], acc);
      sh_gates[g] = acc;
    }
    __syncthreads();
    if (tid < NH_) {
      float gi = sh_gates[tid], gf = sh_gates[NH_ + tid];
      float gg = sh_gates[2 * NH_ + tid], go = sh_gates[3 * NH_ + tid];
      float c_new = sigm(gf) * sh_c[tid] + sigm(gi) * tanhf(gg);
      float h_new = sigm(go) * tanhf(c_new);
      sh_c[tid] = c_new; sh_h[tid] = h_new;
      p.h_buf[n * NH_ + tid] = h_new;
    }
    __syncthreads();
    if (tid < NA_) {
      const float* wa = p.W_act + ((size_t)n * NH_) * NA_ + tid;
      float acc = p.b_act[n * NA_ + tid];
      #pragma unroll 4
      for (int d = 0; d < NH_; ++d) acc = fmaf(sh_h[d], wa[(size_t)d * NA_], acc);
      p.out[((size_t)t * N_ + n) * 9 + tid] = acc;
    } else if (tid == NA_) {
      const float* wc = p.W_cri + (size_t)n * 144;
      float acc = p.b_cri[n];
      #pragma unroll 4
      for (int d = 0; d < NH_; ++d) acc = fmaf(sh_h[d], wc[d], acc);
      acc += wc[NH_ + p.acts[(size_t)t * N_ + nb0]];
      acc += wc[NH_ + NA_ + p.acts[(size_t)t * N_ + nb1]];
      p.out[((size_t)t * N_ + n) * 9 + 8] = acc;
    }
    __threadfence();
    grid.sync();
  }
}

extern "C" void kernel_launch(void* const* d_in, const int* in_sizes, int n_in,
                              void* d_out, int out_size, void* d_ws, size_t ws_size,
                              hipStream_t stream) {
  const float* obs    = (const float*)d_in[0];
  const float* fps    = (const float*)d_in[1];
  const float* dones  = (const float*)d_in[2];
  const float* states0= (const float*)d_in[3];
  const float* W_fcx  = (const float*)d_in[4];
  const float* b_fcx  = (const float*)d_in[5];
  const float* W_fcp  = (const float*)d_in[6];
  const float* b_fcp  = (const float*)d_in[7];
  const float* W_fcm  = (const float*)d_in[8];
  const float* b_fcm  = (const float*)d_in[9];
  const float* W_gat  = (const float*)d_in[10];
  const float* a_src  = (const float*)d_in[11];
  const float* a_dst  = (const float*)d_in[12];
  const float* W_ih   = (const float*)d_in[13];
  const float* W_hh   = (const float*)d_in[14];
  const float* b_lstm = (const float*)d_in[15];
  const float* W_act  = (const float*)d_in[16];
  const float* b_act  = (const float*)d_in[17];
  const float* W_cri  = (const float*)d_in[18];
  const float* b_cri  = (const float*)d_in[19];
  const int*   acts   = (const int*)d_in[20];
  const int*   nbr    = (const int*)d_in[21];

  char* ws = (char*)d_ws;
  size_t off = 0;
  float* h_buf   = (float*)(ws + off); off += (size_t)2 * N_ * NH_ * 4;
  float* Wh_buf  = (float*)(ws + off); off += (size_t)2 * N_ * G3_ * 4;
  float* psrc    = (float*)(ws + off); off += 4096;
  float* pdst    = (float*)(ws + off); off += 4096;
  int*   flag_h  = (int*)(ws + off);   off += (size_t)256 * 16 * 4;
  int*   flag_w  = (int*)(ws + off);   off += (size_t)256 * 16 * 4;
  __hip_bfloat16* lstmT = (__hip_bfloat16*)(ws + off); off += (size_t)N_ * G4_ * 512 * 2;
  __hip_bfloat16* gatT  = (__hip_bfloat16*)(ws + off); off += (size_t)G3_ * G3_ * 2;
  __hip_bfloat16* fcxT  = (__hip_bfloat16*)(ws + off); off += (size_t)N_ * NFC_ * DX_ * 2;
  __hip_bfloat16* fcpT  = (__hip_bfloat16*)(ws + off); off += (size_t)N_ * NFC_ * DP_ * 2;
  __hip_bfloat16* fcmT  = (__hip_bfloat16*)(ws + off); off += (size_t)N_ * NFC_ * DM_ * 2;
  __hip_bfloat16* actT  = (__hip_bfloat16*)(ws + off); off += (size_t)N_ * NA_ * NH_ * 2;
  size_t off_base = off;
  __hip_bfloat16* xp = (__hip_bfloat16*)(ws + off);
  size_t off_xp = off + (size_t)T_ * N_ * 256 * 2;

  if (ws_size < off_base) {
    ParamsF p;
    p.obs = obs; p.fps = fps; p.dones = dones; p.states0 = states0;
    p.W_fcx = W_fcx; p.b_fcx = b_fcx; p.W_fcp = W_fcp; p.b_fcp = b_fcp;
    p.W_fcm = W_fcm; p.b_fcm = b_fcm; p.W_gat = W_gat; p.a_src = a_src; p.a_dst = a_dst;
    p.W_ih = W_ih; p.W_hh = W_hh; p.b_lstm = b_lstm;
    p.W_act = W_act; p.b_act = b_act; p.W_cri = W_cri; p.b_cri = b_cri;
    p.acts = acts; p.nbr = nbr; p.out = (float*)d_out;
    p.h_buf = h_buf; p.Wh_buf = Wh_buf; p.dst_buf = psrc;
    void* args[] = { &p };
    hipLaunchCooperativeKernel((const void*)policy_scan_f32, dim3(N_), dim3(512), args, 0, stream);
    return;
  }
  const int use_xp = (ws_size >= off_xp) ? 1 : 0;

  reset_flags<<<dim3(4), dim3(1024), 0, stream>>>(flag_h, flag_w);
  {
    dim3 blk(256);
    build_lstmT<<<dim3(4096), blk, 0, stream>>>(W_ih, W_hh, lstmT);
    transpose_to_bf16<<<dim3(256),  blk, 0, stream>>>(W_gat, gatT, 1,  G3_, G3_);
    transpose_to_bf16<<<dim3(1024), blk, 0, stream>>>(W_fcx, fcxT, N_, DX_, NFC_);
    transpose_to_bf16<<<dim3(256),  blk, 0, stream>>>(W_fcp, fcpT, N_, DP_, NFC_);
    transpose_to_bf16<<<dim3(1024), blk, 0, stream>>>(W_fcm, fcmT, N_, DM_, NFC_);
    transpose_to_bf16<<<dim3(128),  blk, 0, stream>>>(W_act, actT, N_, NH_, NA_);
  }
  if (use_xp) {
    build_xp<<<dim3(N_, 16), dim3(256), 0, stream>>>(obs, fps, fcxT, fcpT, b_fcx, b_fcp, nbr, xp);
  }

  Params p;
  p.obs = obs; p.fps = fps; p.dones = dones; p.states0 = states0;
  p.b_fcx = b_fcx; p.b_fcp = b_fcp; p.b_fcm = b_fcm;
  p.a_src = a_src; p.a_dst = a_dst;
  p.b_lstm = b_lstm; p.b_act = b_act;
  p.W_cri = W_cri; p.b_cri = b_cri;
  p.acts = acts; p.nbr = nbr;
  p.out = (float*)d_out;
  p.h_buf = h_buf; p.Wh_buf = Wh_buf; p.psrc = psrc; p.pdst = pdst;
  p.flag_h = flag_h; p.flag_w = flag_w;
  p.lstmT = lstmT; p.gatT = gatT;
  p.fcxT = fcxT; p.fcpT = fcpT; p.fcmT = fcmT; p.actT = actT;
  p.xp = xp; p.use_xp = use_xp;

  void* args[] = { &p };
  hipLaunchCooperativeKernel((const void*)policy_scan_v10, dim3(256), dim3(1024), args, 0, stream);
}

// Round 11
// 104018.652 us; speedup vs baseline: 1.3657x; 1.3657x over previous
//
#include <hip/hip_runtime.h>
#include <hip/hip_cooperative_groups.h>
#include <hip/hip_bf16.h>
#include <math.h>

namespace cg = cooperative_groups;

#define T_   2048
#define N_   128
#define NS_  64
#define NA_  8
#define NFC_ 128
#define NH_  128
#define DX_  192
#define DP_  16
#define DM_  256
#define G3_  384
#define G4_  512

// ---------------- bf16 helpers ----------------
template<int NW>
__device__ __forceinline__ float dot_bf16T(const __hip_bfloat16* __restrict__ w,
                                           const float* __restrict__ x) {
  const uint4* wv = reinterpret_cast<const uint4*>(w);
  const float4* xv = reinterpret_cast<const float4*>(x);
  float a0 = 0.f, a1 = 0.f, a2 = 0.f, a3 = 0.f;
  #pragma unroll
  for (int i = 0; i < NW; ++i) {
    uint4 u = wv[i];
    float4 x0 = xv[2 * i];
    float4 x1 = xv[2 * i + 1];
    a0 = fmaf(__uint_as_float(u.x << 16),          x0.x, a0);
    a1 = fmaf(__uint_as_float(u.x & 0xffff0000u),  x0.y, a1);
    a2 = fmaf(__uint_as_float(u.y << 16),          x0.z, a2);
    a3 = fmaf(__uint_as_float(u.y & 0xffff0000u),  x0.w, a3);
    a0 = fmaf(__uint_as_float(u.z << 16),          x1.x, a0);
    a1 = fmaf(__uint_as_float(u.z & 0xffff0000u),  x1.y, a1);
    a2 = fmaf(__uint_as_float(u.w << 16),          x1.z, a2);
    a3 = fmaf(__uint_as_float(u.w & 0xffff0000u),  x1.w, a3);
  }
  return (a0 + a1) + (a2 + a3);
}

// 8-elem bf16 dot: one uint4 of weights vs 8 floats
__device__ __forceinline__ float dot8(uint4 u, const float4* __restrict__ x2) {
  float4 x0 = x2[0], x1 = x2[1];
  float a0 = 0.f, a1 = 0.f;
  a0 = fmaf(__uint_as_float(u.x << 16),          x0.x, a0);
  a1 = fmaf(__uint_as_float(u.x & 0xffff0000u),  x0.y, a1);
  a0 = fmaf(__uint_as_float(u.y << 16),          x0.z, a0);
  a1 = fmaf(__uint_as_float(u.y & 0xffff0000u),  x0.w, a1);
  a0 = fmaf(__uint_as_float(u.z << 16),          x1.x, a0);
  a1 = fmaf(__uint_as_float(u.z & 0xffff0000u),  x1.y, a1);
  a0 = fmaf(__uint_as_float(u.w << 16),          x1.z, a0);
  a1 = fmaf(__uint_as_float(u.w & 0xffff0000u),  x1.w, a1);
  return a0 + a1;
}

__device__ __forceinline__ float sigm(float x) { return 1.f / (1.f + expf(-x)); }

__device__ __forceinline__ void spin_ge(int* f, int want) {
  if (__hip_atomic_load(f, __ATOMIC_ACQUIRE, __HIP_MEMORY_SCOPE_AGENT) >= want) return;
  int g = 0;
  while (__hip_atomic_load(f, __ATOMIC_RELAXED, __HIP_MEMORY_SCOPE_AGENT) < want) {
    __builtin_amdgcn_s_sleep(2);
    if (++g > (1 << 27)) break;
  }
  int v = __hip_atomic_load(f, __ATOMIC_ACQUIRE, __HIP_MEMORY_SCOPE_AGENT);
  asm volatile("" :: "v"(v));
}

struct Params {
  const float* obs; const float* fps; const float* dones; const float* states0;
  const float* b_fcx; const float* b_fcp; const float* b_fcm;
  const float* a_src; const float* a_dst;
  const float* b_lstm; const float* b_act;
  const float* W_cri; const float* b_cri;
  const int* acts; const int* nbr;
  float* out;
  float* h_buf;    // [2][N][NH]
  float* Wh_buf;   // [2][N][G3]
  float* psrc;     // [2][N][2]
  float* pdst;     // [2][N][2]
  int* flag_h;     // [256*16]
  int* flag_w;     // [256*16]
  const __hip_bfloat16* lstmT; // [N][G4][512] = [ih(384)|hh(128)]
  const __hip_bfloat16* gatT;  // [G3][G3]
  const __hip_bfloat16* fcxT;  // [N][NFC][DX]
  const __hip_bfloat16* fcpT;  // [N][NFC][DP]
  const __hip_bfloat16* fcmT;  // [N][NFC][DM]
  const __hip_bfloat16* actT;  // [N][NA][NH]
};

// ---------------- prep kernels ----------------
__global__ void transpose_to_bf16(const float* __restrict__ src, __hip_bfloat16* __restrict__ dst,
                                  int A, int D, int G) {
  size_t total = (size_t)A * D * G;
  size_t stride = (size_t)gridDim.x * blockDim.x;
  for (size_t i = (size_t)blockIdx.x * blockDim.x + threadIdx.x; i < total; i += stride) {
    size_t dg = (size_t)D * G;
    size_t a = i / dg;
    size_t r = i - a * dg;
    size_t g = r / D, d = r - g * D;
    dst[i] = __float2bfloat16(src[a * dg + d * G + g]);
  }
}

__global__ void build_lstmT(const float* __restrict__ Wih, const float* __restrict__ Whh,
                            __hip_bfloat16* __restrict__ dst) {
  size_t total = (size_t)N_ * G4_ * 512;
  size_t stride = (size_t)gridDim.x * blockDim.x;
  for (size_t i = (size_t)blockIdx.x * blockDim.x + threadIdx.x; i < total; i += stride) {
    int d = (int)(i & 511);
    size_t r = i >> 9;
    int g = (int)(r & 511);
    int n = (int)(r >> 9);
    float v = (d < G3_) ? Wih[((size_t)n * G3_ + d) * G4_ + g]
                        : Whh[((size_t)n * NH_ + (d - G3_)) * G4_ + g];
    dst[i] = __float2bfloat16(v);
  }
}

__global__ void reset_flags(int* flag_h, int* flag_w) {
  int i = blockIdx.x * blockDim.x + threadIdx.x;
  if (i < 256 * 16) { flag_h[i] = 0; flag_w[i] = 0; }
}

// heads for timestep th. H==0: actor, H==1: critic.
__device__ __forceinline__ void do_heads(const Params& p, int n, int H, int tid, int th,
                                         const float* sh_h, int nb0, int nb1) {
  if (tid >= 64) return;
  if (H == 0) {
    int a = tid >> 3, k = tid & 7;
    const uint4* wv = reinterpret_cast<const uint4*>(p.actT + ((size_t)n * NA_ + a) * NH_);
    const float4* xv = reinterpret_cast<const float4*>(sh_h);
    float pp = 0.f;
    #pragma unroll
    for (int i = 0; i < 2; ++i) {
      pp += dot8(wv[k * 2 + i], xv + (k * 2 + i) * 2);
    }
    pp += __shfl_down(pp, 4, 8);
    pp += __shfl_down(pp, 2, 8);
    pp += __shfl_down(pp, 1, 8);
    if (k == 0) p.out[((size_t)th * N_ + n) * 9 + a] = pp + p.b_act[n * NA_ + a];
  } else {
    const float* wc = p.W_cri + (size_t)n * 144;
    float pp = sh_h[tid] * wc[tid] + sh_h[64 + tid] * wc[64 + tid];
    for (int off = 32; off; off >>= 1) pp += __shfl_down(pp, off);
    if (tid == 0) {
      pp += p.b_cri[n];
      pp += wc[NH_ + p.acts[(size_t)th * N_ + nb0]];
      pp += wc[NH_ + NA_ + p.acts[(size_t)th * N_ + nb1]];
      p.out[((size_t)th * N_ + n) * 9 + 8] = pp;
    }
  }
}

// ---- main: 256 WGs (2/agent) x 1024 thr; fat per-thread streams + LDS i/f cache ----
__global__ void __launch_bounds__(1024, 4) policy_scan_v11(Params p) {
  const int tid = threadIdx.x;
  const int wid = tid >> 6;
  const int lane = tid & 63;
  const int bid = blockIdx.x;
  const int bl  = bid & 127;
  const int n   = ((bl & 7) << 4) | (bl >> 3);   // cluster ring on XCD
  const int H   = bid >> 7;                      // agent half; partner same XCD
  const int nb0 = p.nbr[n * 2 + 0];
  const int nb1 = p.nbr[n * 2 + 1];
  const int bl0 = ((nb0 & 15) << 3) | (nb0 >> 4);
  const int bl1 = ((nb1 & 15) << 3) | (nb1 >> 4);
  const int wg_partner = bid ^ 128;
  const int w0 = wg_partner, w1 = bl0, w2 = bl0 + 128, w3 = bl1, w4 = bl1 + 128;

  // LDS: 128KB cache of gate rows 0..127 (i,f) in [chunk][row] (conflict-free)
  __shared__ __align__(16) uint4 wlds[64 * 128];
  __shared__ __align__(16) float sh_h[NH_];
  __shared__ __align__(16) float sh_c[64];
  __shared__ __align__(16) float sh_xin[DX_];
  __shared__ __align__(16) float sh_pin[DP_];
  __shared__ __align__(16) float sh_min[DM_];
  __shared__ __align__(16) float sh_feat[G3_];
  __shared__ __align__(16) float sh_sx[512];     // [sgat(384) | masked own h(128)]
  __shared__ __align__(16) float sh_gates[256];
  __shared__ __align__(16) float partial[1024];
  __shared__ __align__(16) float red_s[192];
  __shared__ __align__(16) float red_d[192];

  // preload LDS cache: rows 0..127 (gates i,f), all 64 chunks, [chunk][row]
  {
    int r = tid & 127;
    int cbase = tid >> 7;    // 0..7
    int growr = ((r >> 6) << 7) + H * 64 + (r & 63);
    const uint4* src = reinterpret_cast<const uint4*>(
        p.lstmT + ((size_t)n * G4_ + growr) * 512);
    #pragma unroll
    for (int j = 0; j < 8; ++j) {
      int c = j * 8 + cbase;     // 0..63
      wlds[c * 128 + r] = src[c];
    }
  }

  // prologue
  if (tid < 64) {
    sh_c[tid] = p.states0[n * (2 * NH_) + NH_ + H * 64 + tid];
    p.h_buf[n * NH_ + H * 64 + tid] = p.states0[n * (2 * NH_) + H * 64 + tid];
  }
  __syncthreads();
  if (tid == 0) {
    __threadfence();
    __hip_atomic_store(&p.flag_h[bid * 16], 1, __ATOMIC_RELEASE, __HIP_MEMORY_SCOPE_AGENT);
  }

  for (int t = 0; t < T_; ++t) {
    const float keep  = 1.f - p.dones[(size_t)t * N_ + n];
    const float keep0 = 1.f - p.dones[(size_t)t * N_ + nb0];
    const float keep1 = 1.f - p.dones[(size_t)t * N_ + nb1];

    const float* hb_r = p.h_buf  + (size_t)(t & 1) * N_ * NH_;
    float*       hb_w = p.h_buf  + (size_t)((t + 1) & 1) * N_ * NH_;
    float*       whb  = p.Wh_buf + (size_t)(t & 1) * N_ * G3_;
    float*       psb  = p.psrc   + (size_t)(t & 1) * N_ * 2;
    float*       pdb  = p.pdst   + (size_t)(t & 1) * N_ * 2;

    // ---- A: stage obs/fps + flag_h waits ----
    if (tid < DX_) {
      int k = tid >> 6, d = tid & 63;
      int agent = (k == 0) ? n : ((k == 1) ? nb0 : nb1);
      sh_xin[tid] = p.obs[((size_t)t * N_ + agent) * NS_ + d];
    } else if (tid < DX_ + DP_) {
      int u = tid - DX_;
      int k = u >> 3, a = u & 7;
      int agent = (k == 0) ? nb0 : nb1;
      sh_pin[u] = p.fps[((size_t)t * N_ + agent) * NA_ + a];
    } else if (tid >= 960 && tid < 965) {
      int u = tid - 960;
      int wid5 = (u == 0) ? w0 : (u == 1) ? w1 : (u == 2) ? w2 : (u == 3) ? w3 : w4;
      spin_ge(p.flag_h + wid5 * 16, t + 1);
    }
    __syncthreads();   // b1

    // ---- B: h staging ----
    if (tid < NH_) {
      sh_h[tid] = hb_r[n * NH_ + tid];
    } else if (tid < 384) {
      int v = tid - 128;
      int k = v >> 7, f = v & 127;
      int agent = (k == 0) ? nb0 : nb1;
      float kp  = (k == 0) ? keep0 : keep1;
      sh_min[v] = hb_r[agent * NH_ + f] * kp;
    } else if (tid < 512) {
      int f = tid - 384;
      sh_sx[G3_ + f] = hb_r[n * NH_ + f] * keep;
    }
    __syncthreads();   // b2

    // ---- C: heads(t-1) on wave0 threads, then R4-style fat fc streams ----
    if (wid == 0 && t > 0) do_heads(p, n, H, lane, t - 1, sh_h, nb0, nb1);

    if (tid < 512) {                   // fcm: 128 rows x 4-way K(64), dot<8>
      int r = tid & 127, ks = tid >> 7;
      partial[tid] = dot_bf16T<8>(p.fcmT + ((size_t)n * NFC_ + r) * DM_ + ks * 64,
                                  sh_min + ks * 64);
    } else if (tid < 896) {            // fcx: 128 rows x 3-way K(64), dot<8>
      int u = tid - 512;
      int r = u & 127, ks = u >> 7;
      partial[tid] = dot_bf16T<8>(p.fcxT + ((size_t)n * NFC_ + r) * DX_ + ks * 64,
                                  sh_xin + ks * 64);
    } else {                           // fcp: 128 rows, K=16
      int r = tid - 896;
      partial[tid] = dot_bf16T<2>(p.fcpT + ((size_t)n * NFC_ + r) * DP_, sh_pin);
    }
    __syncthreads();   // b3
    if (tid < 128) {
      float a = p.b_fcx[n * NFC_ + tid] + partial[512 + tid] + partial[640 + tid] + partial[768 + tid];
      sh_feat[tid] = fmaxf(a, 0.f);
    } else if (tid < 256) {
      int r = tid - 128;
      float a = p.b_fcp[n * NFC_ + r] + partial[896 + r];
      sh_feat[128 + r] = fmaxf(a, 0.f);
    } else if (tid < 384) {
      int r = tid - 256;
      float a = p.b_fcm[n * NFC_ + r] + partial[r] + partial[128 + r] + partial[256 + r] + partial[384 + r];
      sh_feat[256 + r] = fmaxf(a, 0.f);
    }
    __syncthreads();   // b4

    // ---- D: gat own 192 rows x 4-way K(96), dot<12> (fat per-thread) ----
    if (tid < 768) {
      int ks = tid / 192, r = tid - ks * 192;
      int row = H * 192 + r;
      partial[tid] = dot_bf16T<12>(p.gatT + (size_t)row * G3_ + ks * 96, sh_feat + ks * 96);
    }
    __syncthreads();   // b5
    if (tid < 192) {
      float wh = partial[tid] + partial[192 + tid] + partial[384 + tid] + partial[576 + tid];
      int row = H * 192 + tid;
      whb[n * G3_ + row] = wh;
      red_s[tid] = wh * p.a_src[row];
      red_d[tid] = wh * p.a_dst[row];
    }
    __syncthreads();   // b6
    if (wid == 0) {
      float s = red_s[lane] + red_s[lane + 64] + red_s[lane + 128];
      for (int off = 32; off; off >>= 1) s += __shfl_down(s, off);
      float d = red_d[lane] + red_d[lane + 64] + red_d[lane + 128];
      for (int off = 32; off; off >>= 1) d += __shfl_down(d, off);
      if (lane == 0) {
        psb[n * 2 + H] = s;
        pdb[n * 2 + H] = d;
        __threadfence();
        __hip_atomic_store(&p.flag_w[bid * 16], t + 1, __ATOMIC_RELEASE, __HIP_MEMORY_SCOPE_AGENT);
      }
    } else if (tid >= 960 && tid < 965) {
      int u = tid - 960;
      int wid5 = (u == 0) ? w0 : (u == 1) ? w1 : (u == 2) ? w2 : (u == 3) ? w3 : w4;
      spin_ge(p.flag_w + wid5 * 16, t + 1);
    }
    __syncthreads();   // b7

    // ---- E: attention + sgat ----
    {
      float src_n = psb[n * 2] + psb[n * 2 + 1];
      float e_l = src_n + pdb[nb0 * 2] + pdb[nb0 * 2 + 1];
      float e_s = src_n + pdb[n   * 2] + pdb[n   * 2 + 1];
      float e_r = src_n + pdb[nb1 * 2] + pdb[nb1 * 2 + 1];
      e_l = (e_l >= 0.f) ? e_l : 0.2f * e_l;
      e_s = (e_s >= 0.f) ? e_s : 0.2f * e_s;
      e_r = (e_r >= 0.f) ? e_r : 0.2f * e_r;
      float mx = fmaxf(e_l, fmaxf(e_s, e_r));
      float wl = expf(e_l - mx), wsf = expf(e_s - mx), wr = expf(e_r - mx);
      float inv = 1.f / (wl + wsf + wr);
      wl *= inv; wsf *= inv; wr *= inv;
      if (tid < G3_) {
        float v = wsf * whb[n   * G3_ + tid]
                + wl  * whb[nb0 * G3_ + tid]
                + wr  * whb[nb1 * G3_ + tid];
        sh_sx[tid] = (v > 0.f) ? v : expm1f(v);
      }
    }
    __syncthreads();   // b8

    // ---- F: LSTM gates. tid<512: LDS rows 0..127 (4-way K); tid>=512: streamed
    //      rows 128..255 (4-way K, dot<16> = 16 loads in flight/thread) ----
    {
      const float4* xv = reinterpret_cast<const float4*>(sh_sx);
      float pr;
      if (tid < 512) {
        int r = tid & 127, ks = tid >> 7;
        float a0 = 0.f, a1 = 0.f;
        #pragma unroll
        for (int i = 0; i < 16; ++i) {
          int c = ks * 16 + i;
          uint4 u = wlds[c * 128 + r];
          float4 x0 = xv[c * 2], x1 = xv[c * 2 + 1];
          a0 = fmaf(__uint_as_float(u.x << 16),          x0.x, a0);
          a1 = fmaf(__uint_as_float(u.x & 0xffff0000u),  x0.y, a1);
          a0 = fmaf(__uint_as_float(u.y << 16),          x0.z, a0);
          a1 = fmaf(__uint_as_float(u.y & 0xffff0000u),  x0.w, a1);
          a0 = fmaf(__uint_as_float(u.z << 16),          x1.x, a0);
          a1 = fmaf(__uint_as_float(u.z & 0xffff0000u),  x1.y, a1);
          a0 = fmaf(__uint_as_float(u.w << 16),          x1.z, a0);
          a1 = fmaf(__uint_as_float(u.w & 0xffff0000u),  x1.w, a1);
        }
        pr = a0 + a1;
      } else {
        int u2 = tid - 512;
        int r2 = u2 & 127, ks = u2 >> 7;
        int ridx = 128 + r2;
        int gr = (ridx >> 6) * 128 + H * 64 + (ridx & 63);
        pr = dot_bf16T<16>(p.lstmT + ((size_t)n * G4_ + gr) * 512 + ks * 128,
                           sh_sx + ks * 128);
      }
      partial[tid] = pr;
    }
    __syncthreads();   // b9
    if (tid < 256) {
      float s;
      if (tid < 128) {
        s = partial[tid] + partial[128 + tid] + partial[256 + tid] + partial[384 + tid];
      } else {
        int r = tid - 128;
        s = partial[512 + r] + partial[640 + r] + partial[768 + r] + partial[896 + r];
      }
      sh_gates[tid] = s + p.b_lstm[n * G4_ + (tid >> 6) * 128 + H * 64 + (tid & 63)];
    }
    __syncthreads();   // b10

    // ---- G: wave0 state update + publish h half ----
    if (wid == 0) {
      float gi = sh_gates[lane];
      float gf = sh_gates[64 + lane];
      float gg = sh_gates[128 + lane];
      float go = sh_gates[192 + lane];
      float c_new = sigm(gf) * (sh_c[lane] * keep) + sigm(gi) * tanhf(gg);
      float h_new = sigm(go) * tanhf(c_new);
      sh_c[lane] = c_new;
      hb_w[n * NH_ + H * 64 + lane] = h_new;
      if (lane == 0) {
        __threadfence();
        __hip_atomic_store(&p.flag_h[bid * 16], t + 2, __ATOMIC_RELEASE, __HIP_MEMORY_SCOPE_AGENT);
      }
    }
    // next iteration's b1 synchronizes; A touches disjoint LDS
  }

  // ---- tail: heads for t = T-1 ----
  if (tid == 0) spin_ge(p.flag_h + wg_partner * 16, T_ + 1);
  __syncthreads();
  if (tid < NH_) sh_h[tid] = p.h_buf[(size_t)(T_ & 1) * N_ * NH_ + n * NH_ + tid];
  __syncthreads();
  do_heads(p, n, H, tid, T_ - 1, sh_h, nb0, nb1);
}

// ---------------- fallback: fp32 grid-sync kernel (ws too small) ----------------
struct ParamsF {
  const float* obs; const float* fps; const float* dones; const float* states0;
  const float* W_fcx; const float* b_fcx;
  const float* W_fcp; const float* b_fcp;
  const float* W_fcm; const float* b_fcm;
  const float* W_gat; const float* a_src; const float* a_dst;
  const float* W_ih;  const float* W_hh;  const float* b_lstm;
  const float* W_act; const float* b_act;
  const float* W_cri; const float* b_cri;
  const int* acts; const int* nbr;
  float* out; float* h_buf; float* Wh_buf; float* dst_buf;
};

__global__ void __launch_bounds__(512) policy_scan_f32(ParamsF p) {
  cg::grid_group grid = cg::this_grid();
  const int tid = threadIdx.x;
  const int n   = blockIdx.x;
  const int nb0 = p.nbr[n * 2 + 0];
  const int nb1 = p.nbr[n * 2 + 1];
  __shared__ float sh_h[NH_], sh_c[NH_], sh_xin[DX_], sh_pin[DP_], sh_min[DM_];
  __shared__ float sh_feat[G3_], sh_Wh[G3_], sh_sgat[G3_], sh_gates[G4_], sh_src;
  if (tid < NH_) {
    float h0 = p.states0[n * (2 * NH_) + tid];
    float c0 = p.states0[n * (2 * NH_) + NH_ + tid];
    sh_h[tid] = h0; sh_c[tid] = c0; p.h_buf[n * NH_ + tid] = h0;
  }
  __threadfence();
  grid.sync();
  for (int t = 0; t < T_; ++t) {
    const float keep  = 1.f - p.dones[(size_t)t * N_ + n];
    const float keep0 = 1.f - p.dones[(size_t)t * N_ + nb0];
    const float keep1 = 1.f - p.dones[(size_t)t * N_ + nb1];
    if (tid < NH_) { sh_h[tid] *= keep; sh_c[tid] *= keep; }
    if (tid < DX_) {
      int k = tid >> 6, d = tid & 63;
      int agent = (k == 0) ? n : ((k == 1) ? nb0 : nb1);
      sh_xin[tid] = p.obs[((size_t)t * N_ + agent) * NS_ + d];
    }
    {
      int u = tid - DX_;
      if (u >= 0 && u < DP_) {
        int k = u >> 3, a = u & 7;
        sh_pin[u] = p.fps[((size_t)t * N_ + ((k == 0) ? nb0 : nb1)) * NA_ + a];
      }
      int v = tid - (DX_ + DP_);
      if (v >= 0 && v < DM_) {
        int k = v >> 7, f = v & 127;
        sh_min[v] = p.h_buf[((k == 0) ? nb0 : nb1) * NH_ + f] * ((k == 0) ? keep0 : keep1);
      }
    }
    __syncthreads();
    if (tid < NFC_) {
      const float* w = p.W_fcx + ((size_t)n * DX_) * NFC_ + tid;
      float acc = p.b_fcx[n * NFC_ + tid];
      #pragma unroll 4
      for (int d = 0; d < DX_; ++d) acc = fmaf(sh_xin[d], w[(size_t)d * NFC_], acc);
      sh_feat[tid] = fmaxf(acc, 0.f);
    } else if (tid < 2 * NFC_) {
      int f = tid - NFC_;
      const float* w = p.W_fcp + ((size_t)n * DP_) * NFC_ + f;
      float acc = p.b_fcp[n * NFC_ + f];
      #pragma unroll
      for (int d = 0; d < DP_; ++d) acc = fmaf(sh_pin[d], w[(size_t)d * NFC_], acc);
      sh_feat[NFC_ + f] = fmaxf(acc, 0.f);
    } else if (tid < 3 * NFC_) {
      int f = tid - 2 * NFC_;
      const float* w = p.W_fcm + ((size_t)n * DM_) * NFC_ + f;
      float acc = p.b_fcm[n * NFC_ + f];
      #pragma unroll 4
      for (int d = 0; d < DM_; ++d) acc = fmaf(sh_min[d], w[(size_t)d * NFC_], acc);
      sh_feat[2 * NFC_ + f] = fmaxf(acc, 0.f);
    }
    __syncthreads();
    if (tid < G3_) {
      const float* w = p.W_gat + tid;
      float acc = 0.f;
      #pragma unroll 4
      for (int d = 0; d < G3_; ++d) acc = fmaf(sh_feat[d], w[(size_t)d * G3_], acc);
      sh_Wh[tid] = acc;
      p.Wh_buf[n * G3_ + tid] = acc;
    }
    __syncthreads();
    if (tid < 64) {
      float s = 0.f;
      for (int g = tid; g < G3_; g += 64) s += sh_Wh[g] * p.a_src[g];
      for (int off = 32; off; off >>= 1) s += __shfl_down(s, off);
      if (tid == 0) sh_src = s;
    } else if (tid < 128) {
      int l = tid - 64;
      float s = 0.f;
      for (int g = l; g < G3_; g += 64) s += sh_Wh[g] * p.a_dst[g];
      for (int off = 32; off; off >>= 1) s += __shfl_down(s, off);
      if (l == 0) p.dst_buf[n] = s;
    }
    __threadfence();
    grid.sync();
    const float src_n = sh_src;
    float e_l = src_n + p.dst_buf[nb0];
    float e_s = src_n + p.dst_buf[n];
    float e_r = src_n + p.dst_buf[nb1];
    e_l = (e_l >= 0.f) ? e_l : 0.2f * e_l;
    e_s = (e_s >= 0.f) ? e_s : 0.2f * e_s;
    e_r = (e_r >= 0.f) ? e_r : 0.2f * e_r;
    float mx = fmaxf(e_l, fmaxf(e_s, e_r));
    float wl = expf(e_l - mx), wsf = expf(e_s - mx), wr = expf(e_r - mx);
    float inv = 1.f / (wl + wsf + wr);
    wl *= inv; wsf *= inv; wr *= inv;
    if (tid < G3_) {
      float v = wsf * sh_Wh[tid] + wl * p.Wh_buf[nb0 * G3_ + tid] + wr * p.Wh_buf[nb1 * G3_ + tid];
      sh_sgat[tid] = (v > 0.f) ? v : expm1f(v);
    }
    __syncthreads();
    {
      const int g = tid;
      const float* wih = p.W_ih + ((size_t)n * G3_) * G4_ + g;
      const float* whh = p.W_hh + ((size_t)n * NH_) * G4_ + g;
      float acc = p.b_lstm[n * G4_ + g];
      #pragma unroll 4
      for (int d = 0; d < G3_; ++d) acc = fmaf(sh_sgat[d], wih[(size_t)d * G4_], acc);
      #pragma unroll 4
      for (int d = 0; d < NH_; ++d) acc = fmaf(sh_h[d], whh[(size_t)d * G4_], acc);
      sh_gates[g] = acc;
    }
    __syncthreads();
    if (tid < NH_) {
      float gi = sh_gates[tid], gf = sh_gates[NH_ + tid];
      float gg = sh_gates[2 * NH_ + tid], go = sh_gates[3 * NH_ + tid];
      float c_new = sigm(gf) * sh_c[tid] + sigm(gi) * tanhf(gg);
      float h_new = sigm(go) * tanhf(c_new);
      sh_c[tid] = c_new; sh_h[tid] = h_new;
      p.h_buf[n * NH_ + tid] = h_new;
    }
    __syncthreads();
    if (tid < NA_) {
      const float* wa = p.W_act + ((size_t)n * NH_) * NA_ + tid;
      float acc = p.b_act[n * NA_ + tid];
      #pragma unroll 4
      for (int d = 0; d < NH_; ++d) acc = fmaf(sh_h[d], wa[(size_t)d * NA_], acc);
      p.out[((size_t)t * N_ + n) * 9 + tid] = acc;
    } else if (tid == NA_) {
      const float* wc = p.W_cri + (size_t)n * 144;
      float acc = p.b_cri[n];
      #pragma unroll 4
      for (int d = 0; d < NH_; ++d) acc = fmaf(sh_h[d], wc[d], acc);
      acc += wc[NH_ + p.acts[(size_t)t * N_ + nb0]];
      acc += wc[NH_ + NA_ + p.acts[(size_t)t * N_ + nb1]];
      p.out[((size_t)t * N_ + n) * 9 + 8] = acc;
    }
    __threadfence();
    grid.sync();
  }
}

extern "C" void kernel_launch(void* const* d_in, const int* in_sizes, int n_in,
                              void* d_out, int out_size, void* d_ws, size_t ws_size,
                              hipStream_t stream) {
  const float* obs    = (const float*)d_in[0];
  const float* fps    = (const float*)d_in[1];
  const float* dones  = (const float*)d_in[2];
  const float* states0= (const float*)d_in[3];
  const float* W_fcx  = (const float*)d_in[4];
  const float* b_fcx  = (const float*)d_in[5];
  const float* W_fcp  = (const float*)d_in[6];
  const float* b_fcp  = (const float*)d_in[7];
  const float* W_fcm  = (const float*)d_in[8];
  const float* b_fcm  = (const float*)d_in[9];
  const float* W_gat  = (const float*)d_in[10];
  const float* a_src  = (const float*)d_in[11];
  const float* a_dst  = (const float*)d_in[12];
  const float* W_ih   = (const float*)d_in[13];
  const float* W_hh   = (const float*)d_in[14];
  const float* b_lstm = (const float*)d_in[15];
  const float* W_act  = (const float*)d_in[16];
  const float* b_act  = (const float*)d_in[17];
  const float* W_cri  = (const float*)d_in[18];
  const float* b_cri  = (const float*)d_in[19];
  const int*   acts   = (const int*)d_in[20];
  const int*   nbr    = (const int*)d_in[21];

  char* ws = (char*)d_ws;
  size_t off = 0;
  float* h_buf   = (float*)(ws + off); off += (size_t)2 * N_ * NH_ * 4;
  float* Wh_buf  = (float*)(ws + off); off += (size_t)2 * N_ * G3_ * 4;
  float* psrc    = (float*)(ws + off); off += 4096;
  float* pdst    = (float*)(ws + off); off += 4096;
  int*   flag_h  = (int*)(ws + off);   off += (size_t)256 * 16 * 4;
  int*   flag_w  = (int*)(ws + off);   off += (size_t)256 * 16 * 4;
  __hip_bfloat16* lstmT = (__hip_bfloat16*)(ws + off); off += (size_t)N_ * G4_ * 512 * 2;
  __hip_bfloat16* gatT  = (__hip_bfloat16*)(ws + off); off += (size_t)G3_ * G3_ * 2;
  __hip_bfloat16* fcxT  = (__hip_bfloat16*)(ws + off); off += (size_t)N_ * NFC_ * DX_ * 2;
  __hip_bfloat16* fcpT  = (__hip_bfloat16*)(ws + off); off += (size_t)N_ * NFC_ * DP_ * 2;
  __hip_bfloat16* fcmT  = (__hip_bfloat16*)(ws + off); off += (size_t)N_ * NFC_ * DM_ * 2;
  __hip_bfloat16* actT  = (__hip_bfloat16*)(ws + off); off += (size_t)N_ * NA_ * NH_ * 2;

  if (ws_size < off) {
    ParamsF p;
    p.obs = obs; p.fps = fps; p.dones = dones; p.states0 = states0;
    p.W_fcx = W_fcx; p.b_fcx = b_fcx; p.W_fcp = W_fcp; p.b_fcp = b_fcp;
    p.W_fcm = W_fcm; p.b_fcm = b_fcm; p.W_gat = W_gat; p.a_src = a_src; p.a_dst = a_dst;
    p.W_ih = W_ih; p.W_hh = W_hh; p.b_lstm = b_lstm;
    p.W_act = W_act; p.b_act = b_act; p.W_cri = W_cri; p.b_cri = b_cri;
    p.acts = acts; p.nbr = nbr; p.out = (float*)d_out;
    p.h_buf = h_buf; p.Wh_buf = Wh_buf; p.dst_buf = psrc;
    void* args[] = { &p };
    hipLaunchCooperativeKernel((const void*)policy_scan_f32, dim3(N_), dim3(512), args, 0, stream);
    return;
  }

  reset_flags<<<dim3(4), dim3(1024), 0, stream>>>(flag_h, flag_w);
  {
    dim3 blk(256);
    build_lstmT<<<dim3(4096), blk, 0, stream>>>(W_ih, W_hh, lstmT);
    transpose_to_bf16<<<dim3(256),  blk, 0, stream>>>(W_gat, gatT, 1,  G3_, G3_);
    transpose_to_bf16<<<dim3(1024), blk, 0, stream>>>(W_fcx, fcxT, N_, DX_, NFC_);
    transpose_to_bf16<<<dim3(256),  blk, 0, stream>>>(W_fcp, fcpT, N_, DP_, NFC_);
    transpose_to_bf16<<<dim3(1024), blk, 0, stream>>>(W_fcm, fcmT, N_, DM_, NFC_);
    transpose_to_bf16<<<dim3(128),  blk, 0, stream>>>(W_act, actT, N_, NH_, NA_);
  }

  Params p;
  p.obs = obs; p.fps = fps; p.dones = dones; p.states0 = states0;
  p.b_fcx = b_fcx; p.b_fcp = b_fcp; p.b_fcm = b_fcm;
  p.a_src = a_src; p.a_dst = a_dst;
  p.b_lstm = b_lstm; p.b_act = b_act;
  p.W_cri = W_cri; p.b_cri = b_cri;
  p.acts = acts; p.nbr = nbr;
  p.out = (float*)d_out;
  p.h_buf = h_buf; p.Wh_buf = Wh_buf; p.psrc = psrc; p.pdst = pdst;
  p.flag_h = flag_h; p.flag_w = flag_w;
  p.lstmT = lstmT; p.gatT = gatT;
  p.fcxT = fcxT; p.fcpT = fcpT; p.fcmT = fcmT; p.actT = actT;

  void* args[] = { &p };
  hipLaunchCooperativeKernel((const void*)policy_scan_v11, dim3(256), dim3(1024), args, 0, stream);
}